// Round 1
// baseline (324.457 us; speedup 1.0000x reference)
//
#include <hip/hip_runtime.h>
#include <math.h>

#define BATCH 16
#define NPRED 25000
#define MTGT  64
#define KPT   4
#define BLK   256
#define PRED_PER_BLK (BLK * KPT)                       // 1024
#define CHUNKS ((NPRED + PRED_PER_BLK - 1) / PRED_PER_BLK)  // 25

__device__ __forceinline__ float focal_term(float x, float t) {
    // mirrors reference focal_loss elementwise (ALPHA=0.25, GAMMA=2)
    float prob = 1.0f / (1.0f + expf(-x));
    float ce = fmaxf(x, 0.0f) - x * t + log1pf(expf(-fabsf(x)));
    float p_t = prob * t + (1.0f - prob) * (1.0f - t);
    float alpha_t = 0.25f * t + 0.75f * (1.0f - t);
    p_t = fminf(fmaxf(p_t, 1e-6f), 1.0f - 1e-6f);
    float om = 1.0f - p_t;
    return alpha_t * om * om * ce;
}

__global__ __launch_bounds__(BLK) void iou_argmax_kernel(
    const float* __restrict__ preds,    // (B, N, 5)
    const float* __restrict__ targets,  // (B, M, 4) xyxy
    unsigned long long* __restrict__ part,  // (B, CHUNKS, M) packed (iou_bits<<32)|~n
    float* __restrict__ focal0)             // (B,) pre-zeroed
{
    const int b = blockIdx.y;
    const int chunk = blockIdx.x;
    const int t = threadIdx.x;
    const int lane = t & 63;
    const int wave = t >> 6;

    __shared__ float tg[MTGT * 4];
    __shared__ unsigned long long smax[MTGT * 4];  // [m][wave]
    __shared__ float sfocal[4];

    if (t < MTGT * 4) tg[t] = targets[b * MTGT * 4 + t];
    __syncthreads();

    // load my KPT pred boxes, convert cxcywh->xyxy (w,h clamped), area
    float bx1[KPT], by1[KPT], bx2[KPT], by2[KPT], barea[KPT];
    bool valid[KPT];
    float fsum = 0.0f;
    const int base = chunk * PRED_PER_BLK;
    for (int k = 0; k < KPT; k++) {
        int n = base + k * BLK + t;
        valid[k] = (n < NPRED);
        if (valid[k]) {
            const float* p = preds + ((long)b * NPRED + n) * 5;
            float cx = p[0], cy = p[1];
            float w = fmaxf(p[2], 1e-4f);
            float h = fmaxf(p[3], 1e-4f);
            float cf = p[4];
            bx1[k] = cx - w / 2.0f; by1[k] = cy - h / 2.0f;
            bx2[k] = cx + w / 2.0f; by2[k] = cy + h / 2.0f;
            barea[k] = (bx2[k] - bx1[k]) * (by2[k] - by1[k]);
            fsum += focal_term(cf, 0.0f);
        }
    }

    // per-target argmax over this block's preds
    for (int m = 0; m < MTGT; m++) {
        float tx1 = tg[m * 4 + 0], ty1 = tg[m * 4 + 1];
        float tx2 = tg[m * 4 + 2], ty2 = tg[m * 4 + 3];
        float tarea = (tx2 - tx1) * (ty2 - ty1);
        unsigned long long best = 0ull;
        for (int k = 0; k < KPT; k++) {
            if (!valid[k]) continue;
            float ltx = fmaxf(bx1[k], tx1);
            float lty = fmaxf(by1[k], ty1);
            float rbx = fminf(bx2[k], tx2);
            float rby = fminf(by2[k], ty2);
            float iw = fmaxf(rbx - ltx, 0.0f);
            float ih = fmaxf(rby - lty, 0.0f);
            float inter = iw * ih;
            float iou = inter / (barea[k] + tarea - inter);
            unsigned int n = (unsigned int)(base + k * BLK + t);
            unsigned long long pk =
                ((unsigned long long)__float_as_uint(iou) << 32) | (unsigned int)(~n);
            best = (pk > best) ? pk : best;
        }
        for (int off = 32; off > 0; off >>= 1) {
            unsigned long long o = __shfl_down(best, off);
            best = (o > best) ? o : best;
        }
        if (lane == 0) smax[m * 4 + wave] = best;
    }

    // focal(conf, 0) block partial sum
    for (int off = 32; off > 0; off >>= 1) fsum += __shfl_down(fsum, off);
    if (lane == 0) sfocal[wave] = fsum;
    __syncthreads();

    if (t < MTGT) {
        unsigned long long v = smax[t * 4 + 0];
        unsigned long long v1 = smax[t * 4 + 1]; v = (v1 > v) ? v1 : v;
        unsigned long long v2 = smax[t * 4 + 2]; v = (v2 > v) ? v2 : v;
        unsigned long long v3 = smax[t * 4 + 3]; v = (v3 > v) ? v3 : v;
        part[((long)b * CHUNKS + chunk) * MTGT + t] = v;
    }
    if (t == 0) {
        atomicAdd(&focal0[b], sfocal[0] + sfocal[1] + sfocal[2] + sfocal[3]);
    }
}

__global__ __launch_bounds__(64) void finalize_kernel(
    const float* __restrict__ preds,
    const float* __restrict__ targets,
    const unsigned long long* __restrict__ part,
    const float* __restrict__ focal0,
    float* __restrict__ out)  // pre-zeroed scalar
{
    const int b = blockIdx.x;
    const int t = threadIdx.x;  // one wave of 64 = one thread per target

    __shared__ float sval[MTGT];
    __shared__ int sidx[MTGT];
    __shared__ unsigned char smask[MTGT];

    unsigned long long best = 0ull;
    for (int c = 0; c < CHUNKS; c++) {
        unsigned long long v = part[((long)b * CHUNKS + c) * MTGT + t];
        best = (v > best) ? v : best;
    }
    sval[t] = __uint_as_float((unsigned int)(best >> 32));
    sidx[t] = (int)(~(unsigned int)best);
    __syncthreads();

    // sequential greedy match (M=64, trivial)
    if (t == 0) {
        for (int m = 0; m < MTGT; m++) {
            bool ok = sval[m] > 0.2f;
            if (ok) {
                int id = sidx[m];
                for (int mm = 0; mm < m; mm++) {
                    if (smask[mm] && sidx[mm] == id) { ok = false; break; }
                }
            }
            smask[m] = ok ? 1 : 0;
        }
    }
    __syncthreads();

    float csum = 0.0f, dsum = 0.0f;
    int cnt = 0;
    if (smask[t]) {
        int id = sidx[t];
        const float* p = preds + ((long)b * NPRED + id) * 5;
        float cx = p[0], cy = p[1];
        float w = fmaxf(p[2], 1e-4f);
        float h = fmaxf(p[3], 1e-4f);
        float cf = p[4];
        float x1p = cx - w / 2.0f, y1p = cy - h / 2.0f;
        float x2p = cx + w / 2.0f, y2p = cy + h / 2.0f;
        const float* tgp = targets + ((long)b * MTGT + t) * 4;
        float x1t = tgp[0], y1t = tgp[1], x2t = tgp[2], y2t = tgp[3];

        // ciou_loss, op-order per reference, EPS=1e-7
        float ltx = fmaxf(x1p, x1t), lty = fmaxf(y1p, y1t);
        float rbx = fminf(x2p, x2t), rby = fminf(y2p, y2t);
        float inter = fmaxf(rbx - ltx, 0.0f) * fmaxf(rby - lty, 0.0f);
        float uni = (x2p - x1p) * (y2p - y1p) + (x2t - x1t) * (y2t - y1t) - inter;
        float iou = inter / (uni + 1e-7f);
        float cx1 = fminf(x1p, x1t), cy1 = fminf(y1p, y1t);
        float cx2 = fmaxf(x2p, x2t), cy2 = fmaxf(y2p, y2t);
        float dx = cx2 - cx1, dy = cy2 - cy1;
        float diag = dx * dx + dy * dy + 1e-7f;
        float ex = x1p + x2p - x1t - x2t;
        float ey = y1p + y2p - y1t - y2t;
        float centers = (ex * ex + ey * ey) / 4.0f;
        float diou = 1.0f - iou + centers / diag;
        float wp = x2p - x1p, hp = y2p - y1p;
        float wt = x2t - x1t, ht = y2t - y1t;
        float dat = atanf(wt / ht) - atanf(wp / hp);
        float v = 0.40528473f * (dat * dat);   // 4/pi^2
        float alpha = v / (1.0f - iou + v + 1e-7f);
        csum = diou + alpha * v;
        cnt = 1;
        dsum = focal_term(cf, 1.0f) - focal_term(cf, 0.0f);
    }

    for (int off = 32; off > 0; off >>= 1) {
        csum += __shfl_down(csum, off);
        dsum += __shfl_down(dsum, off);
        cnt  += __shfl_down(cnt, off);
    }
    if (t == 0) {
        float conf = (focal0[b] + dsum) / (float)NPRED;
        float per = conf;
        if (cnt > 0) per += csum / (float)cnt;
        atomicAdd(out, per * (1.0f / (float)BATCH));
    }
}

extern "C" void kernel_launch(void* const* d_in, const int* in_sizes, int n_in,
                              void* d_out, int out_size, void* d_ws, size_t ws_size,
                              hipStream_t stream) {
    const float* preds = (const float*)d_in[0];     // (16, 25000, 5) f32
    const float* targets = (const float*)d_in[1];   // (16, 64, 4) f32
    float* out = (float*)d_out;

    float* focal0 = (float*)d_ws;  // BATCH floats
    unsigned long long* part = (unsigned long long*)((char*)d_ws + 256);
    // part needs BATCH*CHUNKS*MTGT*8 = 204800 bytes

    hipMemsetAsync(d_out, 0, sizeof(float), stream);
    hipMemsetAsync(d_ws, 0, 256, stream);

    dim3 gridA(CHUNKS, BATCH);
    iou_argmax_kernel<<<gridA, BLK, 0, stream>>>(preds, targets, part, focal0);
    finalize_kernel<<<BATCH, 64, 0, stream>>>(preds, targets, part, focal0, out);
}

// Round 2
// 87.693 us; speedup vs baseline: 3.6999x; 3.6999x over previous
//
#include <hip/hip_runtime.h>
#include <math.h>

#define BATCH 16
#define NPRED 25000
#define MTGT  64
#define CHUNKS 32
#define PPC   800                 // preds per chunk (32*800 = 25600 >= 25000)
#define ABLK  512                 // threads per argmax block (8 waves)
#define WAVES (ABLK / 64)
#define PPW   (PPC / WAVES)       // 100 preds per wave

// ws layout: [0..64)   focal0[BATCH] floats
//            [256..256+8192) gmax[BATCH*MTGT] u64 packed (iou_bits<<32)|~n
#define GMAX_OFF 256
#define WS_ZERO_BYTES (GMAX_OFF + BATCH * MTGT * 8)

__device__ __forceinline__ float focal_term(float x, float t) {
    // mirrors reference focal_loss elementwise (ALPHA=0.25, GAMMA=2)
    float prob = 1.0f / (1.0f + expf(-x));
    float ce = fmaxf(x, 0.0f) - x * t + log1pf(expf(-fabsf(x)));
    float p_t = prob * t + (1.0f - prob) * (1.0f - t);
    float alpha_t = 0.25f * t + 0.75f * (1.0f - t);
    p_t = fminf(fmaxf(p_t, 1e-6f), 1.0f - 1e-6f);
    float om = 1.0f - p_t;
    return alpha_t * om * om * ce;
}

__global__ __launch_bounds__(ABLK) void iou_argmax_kernel(
    const float* __restrict__ preds,    // (B, N, 5)
    const float* __restrict__ targets,  // (B, M, 4) xyxy
    unsigned long long* __restrict__ gmax,  // (B, M) pre-zeroed
    float* __restrict__ focal0)             // (B,) pre-zeroed
{
    const int b = blockIdx.y;
    const int chunk = blockIdx.x;
    const int t = threadIdx.x;
    const int lane = t & 63;
    const int w = t >> 6;

    __shared__ float4 sbox[PPC];                       // xyxy
    __shared__ unsigned long long comb[WAVES][MTGT];
    __shared__ float sfocal[WAVES];

    // ---- stage preds -> LDS (xyxy), accumulate focal(conf, 0) ----
    float fsum = 0.0f;
    for (int idx = t; idx < PPC; idx += ABLK) {
        int n = chunk * PPC + idx;
        float4 bx;
        if (n < NPRED) {
            const float* p = preds + ((long)b * NPRED + n) * 5;
            float cx = p[0], cy = p[1];
            float wd = fmaxf(p[2], 1e-4f);
            float hh = fmaxf(p[3], 1e-4f);
            bx.x = cx - wd / 2.0f;
            bx.y = cy - hh / 2.0f;
            bx.z = cx + wd / 2.0f;
            bx.w = cy + hh / 2.0f;
            fsum += focal_term(p[4], 0.0f);
        } else {
            bx = make_float4(3e8f, 3e8f, 3e8f, 3e8f);  // sentinel: iou = 0
        }
        sbox[idx] = bx;
    }
    // wave-reduce focal partial
    for (int off = 32; off > 0; off >>= 1) fsum += __shfl_down(fsum, off);
    if (lane == 0) sfocal[w] = fsum;

    // ---- my target (lane = target index) ----
    const float* tg = targets + ((long)b * MTGT + lane) * 4;
    float tx1 = tg[0], ty1 = tg[1], tx2 = tg[2], ty2 = tg[3];
    float ta = (tx2 - tx1) * (ty2 - ty1);

    __syncthreads();

    // ---- wave w scans preds [w*PPW, (w+1)*PPW); lane m = its own target ----
    const int nbase = chunk * PPC + w * PPW;
    float best_i = 0.0f, best_d = 1.0f;
    int best_n = nbase;
#pragma unroll 4
    for (int j = 0; j < PPW; j++) {
        float4 bx = sbox[w * PPW + j];                 // LDS broadcast read
        float ap = (bx.z - bx.x) * (bx.w - bx.y);
        float ltx = fmaxf(bx.x, tx1), lty = fmaxf(bx.y, ty1);
        float rbx = fminf(bx.z, tx2), rby = fminf(bx.w, ty2);
        float inter = fmaxf(rbx - ltx, 0.0f) * fmaxf(rby - lty, 0.0f);
        float den = ap + ta - inter;
        // argmax via cross-multiply (no div); strict > keeps lowest n on ties
        bool better = (inter * best_d) > (best_i * den);
        best_i = better ? inter : best_i;
        best_d = better ? den : best_d;
        best_n = better ? (nbase + j) : best_n;
    }
    float iou = best_i / best_d;  // exact IEEE div, reference-identical operands
    comb[w][lane] =
        ((unsigned long long)__float_as_uint(iou) << 32) | (unsigned int)(~best_n);

    __syncthreads();

    if (t < MTGT) {
        unsigned long long v = comb[0][t];
        for (int ww = 1; ww < WAVES; ww++) {
            unsigned long long o = comb[ww][t];
            v = (o > v) ? o : v;
        }
        atomicMax(&gmax[b * MTGT + t], v);
    }
    if (t == 0) {
        float s = 0.0f;
        for (int ww = 0; ww < WAVES; ww++) s += sfocal[ww];
        atomicAdd(&focal0[b], s);
    }
}

__global__ __launch_bounds__(64) void finalize_kernel(
    const float* __restrict__ preds,
    const float* __restrict__ targets,
    const unsigned long long* __restrict__ gmax,
    const float* __restrict__ focal0,
    float* __restrict__ out)  // pre-zeroed scalar
{
    const int b = blockIdx.x;
    const int t = threadIdx.x;  // one wave; lane = target index

    unsigned long long packed = gmax[b * MTGT + t];
    int id = (int)(~(unsigned int)packed);

    const float* tgp = targets + ((long)b * MTGT + t) * 4;
    float x1t = tgp[0], y1t = tgp[1], x2t = tgp[2], y2t = tgp[3];

    // recompute exact pairwise IoU of (winner pred, my target) for threshold
    float x1p = 0.f, y1p = 0.f, x2p = 0.f, y2p = 0.f, cf = 0.f;
    float v = 0.0f;
    if (id >= 0 && id < NPRED) {
        const float* p = preds + ((long)b * NPRED + id) * 5;
        float cx = p[0], cy = p[1];
        float wd = fmaxf(p[2], 1e-4f);
        float hh = fmaxf(p[3], 1e-4f);
        cf = p[4];
        x1p = cx - wd / 2.0f; y1p = cy - hh / 2.0f;
        x2p = cx + wd / 2.0f; y2p = cy + hh / 2.0f;
        float ltx = fmaxf(x1p, x1t), lty = fmaxf(y1p, y1t);
        float rbx = fminf(x2p, x2t), rby = fminf(y2p, y2t);
        float inter = fmaxf(rbx - ltx, 0.0f) * fmaxf(rby - lty, 0.0f);
        float ap = (x2p - x1p) * (y2p - y1p);
        float at = (x2t - x1t) * (y2t - y1t);
        v = inter / (ap + at - inter);
    }

    // greedy match, all-register: lane m accepted iff iou>thr and pred not claimed
    bool accepted = false;
    for (int m = 0; m < MTGT; m++) {
        float vm = __shfl(v, m);
        int im = __shfl(id, m);
        unsigned long long conflict = __ballot(accepted && (id == im));
        bool ok = (vm > 0.2f) && (conflict == 0ull);
        if (t == m) accepted = ok;
    }

    float csum = 0.0f, dsum = 0.0f;
    int cnt = 0;
    if (accepted) {
        // ciou_loss, op-order per reference, EPS=1e-7
        float ltx = fmaxf(x1p, x1t), lty = fmaxf(y1p, y1t);
        float rbx = fminf(x2p, x2t), rby = fminf(y2p, y2t);
        float inter = fmaxf(rbx - ltx, 0.0f) * fmaxf(rby - lty, 0.0f);
        float uni = (x2p - x1p) * (y2p - y1p) + (x2t - x1t) * (y2t - y1t) - inter;
        float iou = inter / (uni + 1e-7f);
        float cx1 = fminf(x1p, x1t), cy1 = fminf(y1p, y1t);
        float cx2 = fmaxf(x2p, x2t), cy2 = fmaxf(y2p, y2t);
        float dx = cx2 - cx1, dy = cy2 - cy1;
        float diag = dx * dx + dy * dy + 1e-7f;
        float ex = x1p + x2p - x1t - x2t;
        float ey = y1p + y2p - y1t - y2t;
        float centers = (ex * ex + ey * ey) / 4.0f;
        float diou = 1.0f - iou + centers / diag;
        float wp = x2p - x1p, hp = y2p - y1p;
        float wt = x2t - x1t, ht = y2t - y1t;
        float dat = atanf(wt / ht) - atanf(wp / hp);
        float vv = 0.40528473f * (dat * dat);  // 4/pi^2
        float alpha = vv / (1.0f - iou + vv + 1e-7f);
        csum = diou + alpha * vv;
        cnt = 1;
        dsum = focal_term(cf, 1.0f) - focal_term(cf, 0.0f);
    }

    for (int off = 32; off > 0; off >>= 1) {
        csum += __shfl_down(csum, off);
        dsum += __shfl_down(dsum, off);
        cnt  += __shfl_down(cnt, off);
    }
    if (t == 0) {
        float conf = (focal0[b] + dsum) / (float)NPRED;
        float per = conf;
        if (cnt > 0) per += csum / (float)cnt;
        atomicAdd(out, per * (1.0f / (float)BATCH));
    }
}

extern "C" void kernel_launch(void* const* d_in, const int* in_sizes, int n_in,
                              void* d_out, int out_size, void* d_ws, size_t ws_size,
                              hipStream_t stream) {
    const float* preds = (const float*)d_in[0];     // (16, 25000, 5) f32
    const float* targets = (const float*)d_in[1];   // (16, 64, 4) f32
    float* out = (float*)d_out;

    float* focal0 = (float*)d_ws;                                    // BATCH floats
    unsigned long long* gmax = (unsigned long long*)((char*)d_ws + GMAX_OFF);

    hipMemsetAsync(d_out, 0, sizeof(float), stream);
    hipMemsetAsync(d_ws, 0, WS_ZERO_BYTES, stream);

    dim3 gridA(CHUNKS, BATCH);
    iou_argmax_kernel<<<gridA, ABLK, 0, stream>>>(preds, targets, gmax, focal0);
    finalize_kernel<<<BATCH, 64, 0, stream>>>(preds, targets, gmax, focal0, out);
}